// Round 8
// baseline (62.132 us; speedup 1.0000x reference)
//
#include <hip/hip_runtime.h>
#include <hip/hip_bf16.h>
#include <math.h>

// Problem dims (fixed by reference): B=64, N=32, S=1024, D=128
#define NB 64
#define NTOK 32
#define NS 1024
#define ND 128

typedef __attribute__((ext_vector_type(8))) short short8;  // 8 x bf16
typedef __attribute__((ext_vector_type(4))) float f32x4;

// 8 fp32 -> 8 bf16 via v_cvt_pk_bf16_f32. q, doc, neg all use this SAME
// function, so any pairing-order quirk cancels in the MFMA dot product.
__device__ __forceinline__ short8 cvt8(float4 a, float4 b) {
    union { unsigned int u[4]; short8 s; } r;
    asm("v_cvt_pk_bf16_f32 %0, %1, %2" : "=v"(r.u[0]) : "v"(a.x), "v"(a.y));
    asm("v_cvt_pk_bf16_f32 %0, %1, %2" : "=v"(r.u[1]) : "v"(a.z), "v"(a.w));
    asm("v_cvt_pk_bf16_f32 %0, %1, %2" : "=v"(r.u[2]) : "v"(b.x), "v"(b.y));
    asm("v_cvt_pk_bf16_f32 %0, %1, %2" : "=v"(r.u[3]) : "v"(b.z), "v"(b.w));
    return r.s;
}

// Fragment layout per 16x128 tile: [ks(4)][lane(64)] short8; lane l = row (l&15),
// k = ks*32 + 8*(l>>4) + j. LDS slot XOR-swizzle (R7-validated, 0 conflicts):
// write slot = ((g>>2)*64+(g&3)*16+row) ^ (g&7); read slot = (ks*64+l) ^
// (((ks&1)<<2)|(l>>4)).

// Fused maxsim. Grid (c=64, bg=4, sh=2): linear id = c + 64*bg + 256*sh ->
// XCD = c%8 (all 8 blocks sharing doc slice c co-XCD). Block: 512 thr = 8
// waves, 16 b's (2/wave, qa in regs). Chunk = 64 doc rows (4 tiles, 16KB bf16),
// 8 chunks, double-buffered 2x16KB LDS, ONE barrier/chunk. Each chunk: 64 MFMA
// per wave; 2 blocks/CU -> 4 waves/SIMD hide staging + barrier latency.
__global__ __launch_bounds__(512, 2) void maxsim_fused(const float* __restrict__ qe,
                                                       const float* __restrict__ dc,
                                                       const float* __restrict__ ng,
                                                       float* __restrict__ score_part,
                                                       float* __restrict__ neg_part) {
    int c = blockIdx.x;
    int bg = blockIdx.y;
    int sh = blockIdx.z;
    int t = threadIdx.x;
    int w = t >> 6, l = t & 63;
    int b0 = bg * 16 + w * 2;  // this wave: b0, b0+1

    __shared__ alignas(16) short lds[2][8192];  // 2 x 16KB (4 tiles each)
    f32x4 zero = {0.f, 0.f, 0.f, 0.f};

    // staging role: threads 0-255 stage tiles {0,1}, 256-511 tiles {2,3};
    // within half: thread covers (row = s>>4, cols 8g..8g+7) of each tile.
    int sidx = t & 255, half = t >> 8;
    int row = sidx >> 4, g = sidx & 15;
    int slotw = (((g >> 2) * 64 + (g & 3) * 16 + row) ^ (g & 7));  // swizzled
    // src for tile T of chunk ch: src0 + (ch*64 + T*16)*ND
    const float* src0 = dc + ((size_t)c * NS + (size_t)sh * 512 + row) * ND + g * 8;

    float4 pa[2], pb[2];  // prefetch: 2 tiles x 32B = 16 VGPR
#pragma unroll
    for (int i = 0; i < 2; ++i) {  // issue chunk-0 loads immediately
        const float* sp = src0 + (half * 2 + i) * 16 * ND;
        pa[i] = ((const float4*)sp)[0];
        pb[i] = ((const float4*)sp)[1];
    }

    // q fragments fp32->bf16 on the fly: qa[bb][m][ks] (64 VGPR)
    short8 qa[2][2][4];
#pragma unroll
    for (int bb = 0; bb < 2; ++bb)
#pragma unroll
        for (int m = 0; m < 2; ++m)
#pragma unroll
            for (int ks = 0; ks < 4; ++ks) {
                const float* sp =
                    qe + ((b0 + bb) * 32 + m * 16 + (l & 15)) * ND + ks * 32 + 8 * (l >> 4);
                qa[bb][m][ks] = cvt8(((const float4*)sp)[0], ((const float4*)sp)[1]);
            }

    if (sh == 0) {  // fused neg partial: tile (b, s-chunk c) of q[b]·neg[b]
#pragma unroll
        for (int bb = 0; bb < 2; ++bb) {
            const float* nt =
                ng + (((b0 + bb) * 64 + c) * 16 + (l & 15)) * ND + 8 * (l >> 4);
            short8 nb[4];
#pragma unroll
            for (int ks = 0; ks < 4; ++ks) {
                const float* sp = nt + ks * 32;
                nb[ks] = cvt8(((const float4*)sp)[0], ((const float4*)sp)[1]);
            }
#pragma unroll
            for (int m = 0; m < 2; ++m) {
                f32x4 acc = zero;
#pragma unroll
                for (int ks = 0; ks < 4; ++ks)
                    acc = __builtin_amdgcn_mfma_f32_16x16x32_bf16(qa[bb][m][ks], nb[ks], acc, 0, 0, 0);
#pragma unroll
                for (int r = 0; r < 4; ++r) {
                    float v = acc[r];
                    v = fmaxf(v, __shfl_xor(v, 1));
                    v = fmaxf(v, __shfl_xor(v, 2));
                    v = fmaxf(v, __shfl_xor(v, 4));
                    v = fmaxf(v, __shfl_xor(v, 8));
                    if ((l & 15) == 0)
                        neg_part[(c * 64 + (b0 + bb)) * 32 + m * 16 + (l >> 4) * 4 + r] = v;
                }
            }
        }
    }

    // write chunk 0 (swizzled), publish
#pragma unroll
    for (int i = 0; i < 2; ++i)
        *(short8*)(&lds[0][((half * 2 + i) * 256 + slotw) * 8]) = cvt8(pa[i], pb[i]);
    __syncthreads();

    f32x4 vmax[2][2];
#pragma unroll
    for (int bb = 0; bb < 2; ++bb)
#pragma unroll
        for (int m = 0; m < 2; ++m)
#pragma unroll
            for (int r = 0; r < 4; ++r) vmax[bb][m][r] = -INFINITY;

    for (int ch = 0; ch < 8; ++ch) {
        int p = ch & 1;
        if (ch + 1 < 8) {  // issue next chunk's loads before compute
#pragma unroll
            for (int i = 0; i < 2; ++i) {
                const float* sp = src0 + ((ch + 1) * 64 + (half * 2 + i) * 16) * ND;
                pa[i] = ((const float4*)sp)[0];
                pb[i] = ((const float4*)sp)[1];
            }
        }
        // compute chunk ch: 4 s-subtiles x (2b x 2m x 4ks) = 64 MFMA
#pragma unroll
        for (int ss = 0; ss < 4; ++ss) {
            short8 bf[4];
#pragma unroll
            for (int ks = 0; ks < 4; ++ks) {
                int rs = (ks * 64 + l) ^ (((ks & 1) << 2) | (l >> 4));
                bf[ks] = *(const short8*)(&lds[p][(ss * 256 + rs) * 8]);
            }
#pragma unroll
            for (int bb = 0; bb < 2; ++bb)
#pragma unroll
                for (int m = 0; m < 2; ++m) {
                    f32x4 acc = zero;
#pragma unroll
                    for (int ks = 0; ks < 4; ++ks)
                        acc = __builtin_amdgcn_mfma_f32_16x16x32_bf16(qa[bb][m][ks], bf[ks], acc, 0, 0, 0);
#pragma unroll
                    for (int r = 0; r < 4; ++r)
                        vmax[bb][m][r] = fmaxf(vmax[bb][m][r], acc[r]);
                }
        }
        if (ch + 1 < 8) {  // stage next chunk (write-after-read safe: prev barrier)
#pragma unroll
            for (int i = 0; i < 2; ++i)
                *(short8*)(&lds[p ^ 1][((half * 2 + i) * 256 + slotw) * 8]) = cvt8(pa[i], pb[i]);
            __syncthreads();  // publish chunk ch+1 (uniform branch)
        }
    }

    // per-n rowmax partial -> score_part[((sh*64 + c)*64 + b)*32 + n]
#pragma unroll
    for (int bb = 0; bb < 2; ++bb)
#pragma unroll
        for (int m = 0; m < 2; ++m)
#pragma unroll
            for (int r = 0; r < 4; ++r) {
                float v = vmax[bb][m][r];
                v = fmaxf(v, __shfl_xor(v, 1));
                v = fmaxf(v, __shfl_xor(v, 2));
                v = fmaxf(v, __shfl_xor(v, 4));
                v = fmaxf(v, __shfl_xor(v, 8));
                if ((l & 15) == 0)
                    score_part[((sh * 64 + c) * 64 + (b0 + bb)) * 32 + m * 16 + (l >> 4) * 4 + r] = v;
            }
}

// Per-b reduction: combine sh-halves -> scores[b][c] (c = lane), reduce
// neg_part over c, then CE + softplus -> bloss[b]. 64 blocks x 64 threads.
__global__ __launch_bounds__(64) void reduce_b(const float* __restrict__ score_part,
                                               const float* __restrict__ neg_part,
                                               const int* __restrict__ offp,
                                               float* __restrict__ bloss) {
    int b = blockIdx.x;
    int c = threadIdx.x;  // one wave
    const float4* p0 = (const float4*)(score_part + (c * 64 + b) * 32);
    const float4* p1 = (const float4*)(score_part + 64 * 64 * 32 + (c * 64 + b) * 32);
    float s = 0.f;
#pragma unroll
    for (int j = 0; j < 8; ++j) {
        float4 a = p0[j], q = p1[j];
        s += fmaxf(a.x, q.x) + fmaxf(a.y, q.y) + fmaxf(a.z, q.z) + fmaxf(a.w, q.w);
    }
    // neg: elementwise max over c of neg_part[c][b][n], then sum over n
    float v[32];
    {
        const float4* np = (const float4*)(neg_part + (c * 64 + b) * 32);
#pragma unroll
        for (int j = 0; j < 8; ++j) {
            float4 a = np[j];
            v[j * 4] = a.x; v[j * 4 + 1] = a.y; v[j * 4 + 2] = a.z; v[j * 4 + 3] = a.w;
        }
    }
#pragma unroll
    for (int off = 1; off < 64; off <<= 1)
#pragma unroll
        for (int j = 0; j < 32; ++j) v[j] = fmaxf(v[j], __shfl_xor(v[j], off));
    float negs = 0.f;
#pragma unroll
    for (int j = 0; j < 32; ++j) negs += v[j];

    const float invT = 50.0f;
    float m = s;
#pragma unroll
    for (int off = 1; off < 64; off <<= 1) m = fmaxf(m, __shfl_xor(m, off));
    float e = expf((s - m) * invT);
#pragma unroll
    for (int off = 1; off < 64; off <<= 1) e += __shfl_xor(e, off);
    float lse = m * invT + logf(e);
    int label = offp[0] + b;
    label = label < 0 ? 0 : (label > 63 ? 63 : label);
    float slabel = __shfl(s, label);
    float pos = __shfl(s, b);
    if (c == 0) {
        float x = (negs - pos) * invT;
        float sp = fmaxf(x, 0.f) + log1pf(expf(-fabsf(x)));
        bloss[b] = sp + lse - slabel * invT;
    }
}

__global__ __launch_bounds__(64) void final_sum(const float* __restrict__ bloss,
                                                float* __restrict__ out) {
    float v = bloss[threadIdx.x];
#pragma unroll
    for (int off = 1; off < 64; off <<= 1) v += __shfl_xor(v, off);
    if (threadIdx.x == 0) out[0] = v * (0.5f / 64.f);
}

extern "C" void kernel_launch(void* const* d_in, const int* in_sizes, int n_in,
                              void* d_out, int out_size, void* d_ws, size_t ws_size,
                              hipStream_t stream) {
    const float* q = (const float*)d_in[0];
    const float* dc = (const float*)d_in[1];
    const float* ng = (const float*)d_in[2];
    const int* offp = (const int*)d_in[3];
    float* out = (float*)d_out;

    // ws: neg_part 512KB @0 | score_part 1MB @0x80000 | bloss @0x180000
    char* ws = (char*)d_ws;
    float* neg_part = (float*)(ws);
    float* score_part = (float*)(ws + 0x80000);
    float* bloss = (float*)(ws + 0x180000);
    if (ws_size < 0x180200) return;

    maxsim_fused<<<dim3(64, 4, 2), 512, 0, stream>>>(q, dc, ng, score_part, neg_part);
    reduce_b<<<64, 64, 0, stream>>>(score_part, neg_part, offp, bloss);
    final_sum<<<1, 64, 0, stream>>>(bloss, out);
}